// Round 8
// baseline (356.539 us; speedup 1.0000x reference)
//
#include <hip/hip_runtime.h>

#define NPROJ 180
#define DH 192
#define DW 384
#define VN 96
#define ZPER 4
#define TILE_U 40
#define TILE_V 14
#define TSIZE (TILE_U * TILE_V)     // 560 pairs per batch tile
#define NPAIR (2 * TSIZE)           // 1120 pairs total (both batches)
#define PSTRIDE (DH * DW)
#define BSTRIDE (NPROJ * DH * DW)

typedef float v2f __attribute__((ext_vector_type(2)));

// Block = 128 threads (2 waves): 16x x 8y, ZPER=4 z, BOTH batches.
// Grid = 6 x 12 x 24 = 1728 blocks -> 6.75 blocks/CU (tail 3.7%, was 19%
// at 864 blocks: the r7 profile showed two ~50%-busy pipes (VALU ~135us,
// LDS ~125us) failing to overlap due to imbalance + 3.4 waves/SIMD).
//
// Footprint re-derived for 16-wide x blocks:
//   |u-uc| <= 1.7575*sqrt((7.5+3.5g)^2+(3.5+7.5g)^2) = 15.5 (g=0.08)
//     -> 40-pair tile, iu0 = floor(uc)-19; u0l in [2,35], taps <= 37 <= 39.
//   |v-vc| <= 3.7 (strictly smaller than r4's proven 4.6) -> keep 14 rows,
//     iv0 = floor(vc)-6.
// Global window [iu0, iu0+40] in [54,331] x rows [24,168] — in-detector.
// Tile entry c = pair (img[c], img[c+1]); bilinear = one ds_read2_b64
// (batch1 via one v_add base bump, offsets 560/600 exceed the 255 imm).
__global__ __launch_bounds__(128) void cone_bp(
    const float* __restrict__ sino,   // [B, P, H, W]
    const float* __restrict__ mats,   // [P, 3, 4]
    float* __restrict__ out)          // [B, Z, Y, X]
{
    __shared__ v2f tile2[2][NPAIR];   // 2 x 8.96 KB

    const int tid = threadIdx.x;
    const int x = blockIdx.x * 16 + (tid & 15);
    const int y = blockIdx.y * 8 + (tid >> 4);
    const int zc = blockIdx.z;

    const float xw = (float)x - 47.5f;
    const float yw = (float)y - 47.5f;
    const float zw0 = (float)(zc * ZPER) - 47.5f;

    // block-center world coords (tile anchoring)
    const float xwc = (float)(blockIdx.x * 16) - 40.0f;   // +7.5 - 47.5
    const float ywc = (float)(blockIdx.y * 8) - 44.0f;    // +3.5 - 47.5
    const float zwc = (float)(zc * ZPER) - 46.0f;         // +1.5 - 47.5

    const float4* __restrict__ M = (const float4*)mats;

    // ---- staging map: li = tid + 128k; 1120 pairs = 8 full + 1 masked ----
    int V[9];           // loop-invariant global float-offsets (incl. batch)
#pragma unroll
    for (int k = 0; k < 9; ++k) {
        int li = tid + 128 * k;
        int bb = (li >= TSIZE) ? 1 : 0;
        int rem = li - bb * TSIZE;
        V[k] = bb * BSTRIDE + (rem / TILE_U) * DW + (rem % TILE_U);
    }

#define ANCHOR(P, IU, IV)                                                   \
    {                                                                       \
        float4 a0 = M[(P) * 3 + 0];                                         \
        float4 a1 = M[(P) * 3 + 1];                                         \
        float4 a2 = M[(P) * 3 + 2];                                         \
        float unc = fmaf(a0.x, xwc, fmaf(a0.y, ywc, a0.w));                 \
        float vnc = fmaf(a1.x, xwc, fmaf(a1.y, ywc, fmaf(a1.z, zwc, a1.w)));\
        float wc  = fmaf(a2.x, xwc, fmaf(a2.y, ywc, a2.w));                 \
        float rwc = __builtin_amdgcn_rcpf(wc);                              \
        IU = __builtin_amdgcn_readfirstlane((int)floorf(unc * rwc) - 19);   \
        IV = __builtin_amdgcn_readfirstlane((int)floorf(vnc * rwc) - 6);    \
    }

    // ---- prologue: anchor + stage p=0 into buffer 0 ----
    int siu, siv;
    ANCHOR(0, siu, siv)
    {
        const float* __restrict__ ps = sino + siv * DW + siu;  // uniform
#pragma unroll
        for (int k = 0; k < 8; ++k)
            tile2[0][tid + 128 * k] = *(const v2f*)(ps + V[k]);
        if (tid < NPAIR - 1024)
            tile2[0][tid + 1024] = *(const v2f*)(ps + V[8]);
    }

    float acc0[ZPER], acc1[ZPER];
#pragma unroll
    for (int k = 0; k < ZPER; ++k) { acc0[k] = 0.0f; acc1[k] = 0.0f; }

    for (int p = 0; p < NPROJ; ++p) {
        __syncthreads();   // buf[p&1] staged; prev sampling of other buf done

        // ---- prefetch p+1 window into registers ----
        v2f g[9];
        int niu = siu, niv = siv;
        const bool has_next = (p + 1 < NPROJ);
        if (has_next) {
            ANCHOR(p + 1, niu, niv)
            const float* __restrict__ ps =
                sino + (p + 1) * PSTRIDE + niv * DW + niu;     // uniform
#pragma unroll
            for (int k = 0; k < 8; ++k)
                g[k] = *(const v2f*)(ps + V[k]);
            if (tid < NPAIR - 1024)
                g[8] = *(const v2f*)(ps + V[8]);
        }

        // ---- sample projection p (both batches) from buf[p&1] ----
        {
            float4 r0 = M[p * 3 + 0];
            float4 r1 = M[p * 3 + 1];
            float4 r2 = M[p * 3 + 2];
            float un  = fmaf(r0.x, xw, fmaf(r0.y, yw, r0.w));
            float vn0 = fmaf(r1.x, xw, fmaf(r1.y, yw, r1.w));
            float w   = fmaf(r2.x, xw, fmaf(r2.y, yw, r2.w));
            float rw  = __builtin_amdgcn_rcpf(w);
            float iw2 = rw * rw;                         // FDK 1/w^2
            float ul  = fmaf(un, rw, -(float)siu);       // tile-local u
            float uf  = floorf(ul);
            float fu  = ul - uf;
            int   u0l = (int)uf;
            float vb  = fmaf(fmaf(r1.z, zw0, vn0), rw, -(float)siv);
            float dv  = r1.z * rw;

            const v2f* __restrict__ tb = tile2[p & 1];

            // phase 1: shared offsets + fv (once for both batches)
            int   o[ZPER];
            float fv[ZPER];
#pragma unroll
            for (int k = 0; k < ZPER; ++k) {
                float v  = fmaf(dv, (float)k, vb);
                float vf = floorf(v);
                fv[k] = v - vf;
                o[k] = (int)vf * TILE_U + u0l;
            }
            // phase 2: all LDS reads (ds_read2_b64 each; 8 in flight)
            v2f A0[ZPER], B0[ZPER], A1[ZPER], B1[ZPER];
#pragma unroll
            for (int k = 0; k < ZPER; ++k) {
                A0[k] = tb[o[k]];
                B0[k] = tb[o[k] + TILE_U];
                A1[k] = tb[o[k] + TSIZE];
                B1[k] = tb[o[k] + TSIZE + TILE_U];
            }
            // phase 3: lerp + accumulate, both batches share fv/fu/iw2
#pragma unroll
            for (int k = 0; k < ZPER; ++k) {
                v2f C0 = A0[k] + (B0[k] - A0[k]) * fv[k];
                v2f C1 = A1[k] + (B1[k] - A1[k]) * fv[k];
                float h0 = fmaf(C0.y - C0.x, fu, C0.x);
                float h1 = fmaf(C1.y - C1.x, fu, C1.x);
                acc0[k] = fmaf(h0, iw2, acc0[k]);
                acc1[k] = fmaf(h1, iw2, acc1[k]);
            }
        }

        // ---- commit prefetched tile to buf[(p+1)&1] ----
        if (has_next) {
            v2f* __restrict__ dst = tile2[(p + 1) & 1];
#pragma unroll
            for (int k = 0; k < 8; ++k)
                dst[tid + 128 * k] = g[k];
            if (tid < NPAIR - 1024)
                dst[tid + 1024] = g[8];
        }
        siu = niu; siv = niv;
    }

    const int zbase = zc * ZPER;
#pragma unroll
    for (int k = 0; k < ZPER; ++k) {
        out[(((size_t)(zbase + k)) * VN + y) * VN + x] = acc0[k];
        out[(((size_t)(VN + zbase + k)) * VN + y) * VN + x] = acc1[k];
    }
#undef ANCHOR
}

extern "C" void kernel_launch(void* const* d_in, const int* in_sizes, int n_in,
                              void* d_out, int out_size, void* d_ws, size_t ws_size,
                              hipStream_t stream) {
    const float* sino = (const float*)d_in[0];   // [2,180,192,384,1] fp32
    const float* mats = (const float*)d_in[1];   // [180,3,4] fp32
    float* out = (float*)d_out;                  // [2,96,96,96,1] fp32

    // grid: 6 x-tiles, 12 y-tiles, 24 z-chunks (both batches per block)
    dim3 grid(VN / 16, VN / 8, VN / ZPER), block(128);
    hipLaunchKernelGGL(cone_bp, grid, block, 0, stream, sino, mats, out);
}

// Round 9
// 327.070 us; speedup vs baseline: 1.0901x; 1.0901x over previous
//
#include <hip/hip_runtime.h>

#define NPROJ 180
#define PHALF 90
#define DH 192
#define DW 384
#define VN 96
#define ZPER 4
#define TILE_U 64
#define TILE_V 14
#define TSIZE (TILE_U * TILE_V)     // 896 pairs per batch tile
#define NPAIR (2 * TSIZE)           // 1792 = 7*256: exact staging, no mask
#define PSTRIDE (DH * DW)
#define BSTRIDE (NPROJ * DH * DW)

typedef float v2f __attribute__((ext_vector_type(2)));

// r9: projection-split. Block = 256 threads (32x x 8y, 8x8 per-wave lane map,
// ZPER=4 z, both batches) over 90 of the 180 projections. Two blocks per
// voxel-tile merge with unsafeAtomicAdd (exactly 2 addends -> order-free;
// d_out zeroed via async memset). Grid 3x12x48 = 1728 blocks = 6912 waves
// (6.75/SIMD, 3.7% tail) vs r7's 3456 (3.4/SIMD, 19% tail) — r7/r8 showed
// both pipes ~50% busy and latency-bound at that depth.
// Single-buffer LDS tile (14 KB, fits 6.75+ blocks/CU); p+1 staging loads
// issue BEFORE sampling p so the 2nd barrier's vmcnt wait is pre-drained.
// Anchors precomputed once into an LDS table (saves ~14 VALU+rcp/proj).
// Geometry bounds all r7-proven: iu0=floor(uc)-31 (u0l in [2,60]),
// iv0=floor(vc)-6 (vi in [1,11]); window in-detector.
__global__ __launch_bounds__(256) void cone_bp(
    const float* __restrict__ sino,   // [B, P, H, W]
    const float* __restrict__ mats,   // [P, 3, 4]
    float* __restrict__ out)          // [B, Z, Y, X]
{
    __shared__ v2f tile2[NPAIR];      // 14 KB, single buffer
    __shared__ int2 anch[PHALF];      // 720 B anchor table

    const int tid = threadIdx.x;
    // 8x8 per-wave lane map (r7-proven conflict level ~1e7)
    const int x = blockIdx.x * 32 + ((tid & 7) | ((tid >> 6) << 3));
    const int y = blockIdx.y * 8 + ((tid >> 3) & 7);
    const int half = (blockIdx.z >= 24) ? 1 : 0;
    const int zc = blockIdx.z - 24 * half;
    const int pbase = half * PHALF;

    const float xw = (float)x - 47.5f;
    const float yw = (float)y - 47.5f;
    const float zw0 = (float)(zc * ZPER) - 47.5f;

    // block-center world coords (tile anchoring)
    const float xwc = (float)(blockIdx.x * 32) - 32.0f;   // +15.5 - 47.5
    const float ywc = (float)(blockIdx.y * 8) - 44.0f;    // +3.5  - 47.5
    const float zwc = (float)(zc * ZPER) - 46.0f;         // +1.5  - 47.5

    const float4* __restrict__ M = (const float4*)mats;

    // ---- anchor table: one projection per thread, once ----
    if (tid < PHALF) {
        int p = pbase + tid;
        float4 a0 = M[p * 3 + 0];
        float4 a1 = M[p * 3 + 1];
        float4 a2 = M[p * 3 + 2];
        float unc = fmaf(a0.x, xwc, fmaf(a0.y, ywc, a0.w));
        float vnc = fmaf(a1.x, xwc, fmaf(a1.y, ywc, fmaf(a1.z, zwc, a1.w)));
        float wc  = fmaf(a2.x, xwc, fmaf(a2.y, ywc, a2.w));
        float rwc = __builtin_amdgcn_rcpf(wc);
        anch[tid] = make_int2((int)floorf(unc * rwc) - 31,
                              (int)floorf(vnc * rwc) - 6);
    }

    // ---- staging map: li = tid + 256k, k<7 covers all 1792 pairs ----
    int V[7];           // loop-invariant global float-offsets (incl. batch)
#pragma unroll
    for (int k = 0; k < 7; ++k) {
        int li = tid + 256 * k;
        int bb = (li >= TSIZE) ? 1 : 0;
        int rem = li - bb * TSIZE;
        V[k] = bb * BSTRIDE + (rem >> 6) * DW + (rem & 63);
    }

    __syncthreads();    // anchor table ready

    // ---- preload proj pbase into registers ----
    int cu, cv;         // anchor of the projection currently in g[]
    {
        int2 a = anch[0];
        cu = __builtin_amdgcn_readfirstlane(a.x);
        cv = __builtin_amdgcn_readfirstlane(a.y);
    }
    v2f g[7];
    {
        const float* __restrict__ ps = sino + pbase * PSTRIDE + cv * DW + cu;
#pragma unroll
        for (int k = 0; k < 7; ++k)
            g[k] = *(const v2f*)(ps + V[k]);
    }

    float acc0[ZPER], acc1[ZPER];
#pragma unroll
    for (int k = 0; k < ZPER; ++k) { acc0[k] = 0.0f; acc1[k] = 0.0f; }

    for (int i = 0; i < PHALF; ++i) {
        __syncthreads();          // tile2 free (prev sampling done)
#pragma unroll
        for (int k = 0; k < 7; ++k)
            tile2[tid + 256 * k] = g[k];     // vmcnt pre-drained by sampling
        const float nfu = -(float)cu;        // sampling anchor (this proj)
        const float nfv = -(float)cv;
        __syncthreads();          // tile2 staged

        // ---- issue p+1 staging loads BEFORE sampling (latency overlap) ----
        if (i + 1 < PHALF) {
            int2 a = anch[i + 1];
            cu = __builtin_amdgcn_readfirstlane(a.x);
            cv = __builtin_amdgcn_readfirstlane(a.y);
            const float* __restrict__ ps =
                sino + (pbase + i + 1) * PSTRIDE + cv * DW + cu;
#pragma unroll
            for (int k = 0; k < 7; ++k)
                g[k] = *(const v2f*)(ps + V[k]);
        }

        // ---- sample projection pbase+i (both batches) ----
        {
            const int p = pbase + i;
            float4 r0 = M[p * 3 + 0];
            float4 r1 = M[p * 3 + 1];
            float4 r2 = M[p * 3 + 2];
            float un  = fmaf(r0.x, xw, fmaf(r0.y, yw, r0.w));
            float vn0 = fmaf(r1.x, xw, fmaf(r1.y, yw, r1.w));
            float w   = fmaf(r2.x, xw, fmaf(r2.y, yw, r2.w));
            float rw  = __builtin_amdgcn_rcpf(w);
            float iw2 = rw * rw;                         // FDK 1/w^2
            float ul  = fmaf(un, rw, nfu);               // tile-local u
            float uf  = floorf(ul);
            float fu  = ul - uf;
            int   u0l = (int)uf;
            float vb  = fmaf(fmaf(r1.z, zw0, vn0), rw, nfv);
            float dv  = r1.z * rw;

            // phase 1: shared offsets + fv (once for both batches)
            int   o[ZPER];
            float fv[ZPER];
#pragma unroll
            for (int k = 0; k < ZPER; ++k) {
                float v  = fmaf(dv, (float)k, vb);
                float vf = floorf(v);
                fv[k] = v - vf;
                o[k] = ((int)vf << 6) + u0l;
            }
            // phase 2: all LDS reads (ds_read2_b64 each; 8 in flight)
            v2f A0[ZPER], B0[ZPER], A1[ZPER], B1[ZPER];
#pragma unroll
            for (int k = 0; k < ZPER; ++k) {
                A0[k] = tile2[o[k]];
                B0[k] = tile2[o[k] + TILE_U];
                A1[k] = tile2[o[k] + TSIZE];
                B1[k] = tile2[o[k] + TSIZE + TILE_U];
            }
            // phase 3: lerp + accumulate, both batches share fv/fu/iw2
#pragma unroll
            for (int k = 0; k < ZPER; ++k) {
                v2f C0 = A0[k] + (B0[k] - A0[k]) * fv[k];
                v2f C1 = A1[k] + (B1[k] - A1[k]) * fv[k];
                float h0 = fmaf(C0.y - C0.x, fu, C0.x);
                float h1 = fmaf(C1.y - C1.x, fu, C1.x);
                acc0[k] = fmaf(h0, iw2, acc0[k]);
                acc1[k] = fmaf(h1, iw2, acc1[k]);
            }
        }
    }

    // ---- merge: exactly 2 blocks per voxel -> order-independent fp32 add ----
    const int zbase = zc * ZPER;
#pragma unroll
    for (int k = 0; k < ZPER; ++k) {
        unsafeAtomicAdd(&out[(((size_t)(zbase + k)) * VN + y) * VN + x],
                        acc0[k]);
        unsafeAtomicAdd(&out[(((size_t)(VN + zbase + k)) * VN + y) * VN + x],
                        acc1[k]);
    }
}

extern "C" void kernel_launch(void* const* d_in, const int* in_sizes, int n_in,
                              void* d_out, int out_size, void* d_ws, size_t ws_size,
                              hipStream_t stream) {
    const float* sino = (const float*)d_in[0];   // [2,180,192,384,1] fp32
    const float* mats = (const float*)d_in[1];   // [180,3,4] fp32
    float* out = (float*)d_out;                  // [2,96,96,96,1] fp32

    // d_out is poisoned before every launch; atomic merge needs zeros
    hipMemsetAsync(out, 0, (size_t)out_size * sizeof(float), stream);

    // grid: 3 x-tiles, 12 y-tiles, 24 z-chunks x 2 projection halves
    dim3 grid(VN / 32, VN / 8, 48), block(256);
    hipLaunchKernelGGL(cone_bp, grid, block, 0, stream, sino, mats, out);
}